// Round 1
// baseline (323.633 us; speedup 1.0000x reference)
//
#include <hip/hip_runtime.h>
#include <math.h>

#define FACE_W 256
#define CH 32
#define BATCH 2
#define OUT_H (2 * FACE_W)   // 512
#define OUT_W (4 * FACE_W)   // 1024
#define N_PIX (OUT_H * OUT_W)

// One thread per output pixel. Grid math (face, bilinear corners, weights)
// is batch/channel-invariant, so compute it once per thread in double
// precision (face-decision margin >> fp64 error; avoids face flips vs the
// numpy reference), then loop over b*c = 64 samples of 4 gathers each.
__global__ __launch_bounds__(256) void cube2equi_kernel(
    const float* __restrict__ in, float* __restrict__ out) {
    int pix = blockIdx.x * blockDim.x + threadIdx.x;
    if (pix >= N_PIX) return;
    int xx = pix & (OUT_W - 1);
    int yy = pix >> 10;  // OUT_W == 1024

    const double PI = 3.14159265358979323846;
    double theta = (2.0 * (xx + 0.5) / OUT_W - 1.0) * PI;
    double phi   = (2.0 * (yy + 0.5) / OUT_H - 1.0) * (PI * 0.5);
    double cph = cos(phi);
    double sx = cph * cos(theta);
    double sy = cph * sin(theta);
    double sz = sin(phi);
    double ax = fabs(sx), ay = fabs(sy), az = fabs(sz);

    const double EPS = 1e-9;
    int face;
    double u, v;
    if (ax >= ay && ax >= az) {
        face = (sx >= 0.0) ? 0 : 1;
        double d = fmax(ax, EPS);
        u = ((face == 0) ? sy : -sy) / d;
        v = sz / d;
    } else if (ay >= az) {
        face = (sy >= 0.0) ? 2 : 3;
        double d = fmax(ay, EPS);
        u = ((face == 2) ? -sx : sx) / d;
        v = sz / d;
    } else {
        face = (sz >= 0.0) ? 4 : 5;
        double d = fmax(az, EPS);
        u = sy / d;
        v = ((face == 4) ? -sx : sx) / d;
    }

    // align_corners=True: [-1,1] -> [0, W-1]
    float px = (float)((u + 1.0) * 0.5 * (FACE_W - 1));
    float py = (float)((v + 1.0) * 0.5 * (FACE_W - 1));
    float fx0 = floorf(px), fy0 = floorf(py);
    float wx = px - fx0, wy = py - fy0;
    int x0 = min(max((int)fx0, 0), FACE_W - 1);
    int x1 = min(max((int)fx0 + 1, 0), FACE_W - 1);
    int y0 = min(max((int)fy0, 0), FACE_W - 1);
    int y1 = min(max((int)fy0 + 1, 0), FACE_W - 1);

    float w00 = (1.0f - wx) * (1.0f - wy);
    float w10 = wx * (1.0f - wy);
    float w01 = (1.0f - wx) * wy;
    float w11 = wx * wy;

    const size_t planeStride = (size_t)FACE_W * FACE_W;        // 65536
    const size_t faceStride  = (size_t)CH * planeStride;       // per-face block
    const size_t batchStride = 6 * faceStride;

    int o00 = y0 * FACE_W + x0;
    int o10 = y0 * FACE_W + x1;
    int o01 = y1 * FACE_W + x0;
    int o11 = y1 * FACE_W + x1;

    const float* fbase = in + (size_t)face * faceStride;
    size_t outPix = (size_t)yy * OUT_W + xx;
    const size_t outPlane = (size_t)OUT_H * OUT_W;

    for (int b = 0; b < BATCH; ++b) {
        const float* bb = fbase + (size_t)b * batchStride;
        float* ob = out + (size_t)b * CH * outPlane + outPix;
        #pragma unroll 4
        for (int c = 0; c < CH; ++c) {
            const float* p = bb + (size_t)c * planeStride;
            float val = p[o00] * w00 + p[o10] * w10 +
                        p[o01] * w01 + p[o11] * w11;
            ob[(size_t)c * outPlane] = val;
        }
    }
}

extern "C" void kernel_launch(void* const* d_in, const int* in_sizes, int n_in,
                              void* d_out, int out_size, void* d_ws, size_t ws_size,
                              hipStream_t stream) {
    const float* in = (const float*)d_in[0];
    float* out = (float*)d_out;
    int threads = 256;
    int blocks = (N_PIX + threads - 1) / threads;
    cube2equi_kernel<<<blocks, threads, 0, stream>>>(in, out);
}